// Round 1
// baseline (213.574 us; speedup 1.0000x reference)
//
#include <hip/hip_runtime.h>

#define NN 5200   // nodes
#define NI 5200   // incidences
#define NH 1000   // hyperedges
#define ND 4096   // feature dim
#define SLOPE 0.01f

// ---------------- CSR build ----------------

__global__ void count_k(const int* __restrict__ hidx, int* __restrict__ ecnt,
                        int* __restrict__ ncnt) {
    int i = blockIdx.x * blockDim.x + threadIdx.x;
    if (i < NI) {
        atomicAdd(&ncnt[hidx[i]], 1);        // node_idx row
        atomicAdd(&ecnt[hidx[NI + i]], 1);   // edge_idx row
    }
}

__device__ void scan_one(const int* __restrict__ cnt, int* __restrict__ off,
                         int* __restrict__ fill, int n, int* lds) {
    int t = threadIdx.x;
    int per = (n + 1023) >> 10;
    int base = t * per;
    int s = 0;
    for (int i = 0; i < per; ++i) {
        int id = base + i;
        if (id < n) s += cnt[id];
    }
    lds[t] = s;
    __syncthreads();
    for (int d = 1; d < 1024; d <<= 1) {
        int v = (t >= d) ? lds[t - d] : 0;
        __syncthreads();
        lds[t] += v;
        __syncthreads();
    }
    int total = lds[1023];
    int run = (t == 0) ? 0 : lds[t - 1];
    for (int i = 0; i < per; ++i) {
        int id = base + i;
        if (id < n) { off[id] = run; fill[id] = run; run += cnt[id]; }
    }
    if (t == 0) off[n] = total;
}

__global__ void __launch_bounds__(1024) scan_k(const int* ecnt, const int* ncnt,
                                               int* eoff, int* noff,
                                               int* efill, int* nfill) {
    __shared__ int lds[1024];
    scan_one(ecnt, eoff, efill, NH, lds);
    __syncthreads();
    scan_one(ncnt, noff, nfill, NN, lds);
}

__global__ void scatter_k(const int* __restrict__ hidx, int* __restrict__ efill,
                          int* __restrict__ nfill, int* __restrict__ elist,
                          int* __restrict__ nlist) {
    int i = blockIdx.x * blockDim.x + threadIdx.x;
    if (i < NI) {
        int p = atomicAdd(&nfill[hidx[i]], 1);
        nlist[p] = i;
        int q = atomicAdd(&efill[hidx[NI + i]], 1);
        elist[q] = i;
    }
}

// ---------------- heavy phases ----------------

// One block per hyperedge: edge_raw[h] = Binv * sum_{incid} features[node]
__global__ void __launch_bounds__(256) edge_k(const float* __restrict__ feat,
        const int* __restrict__ hidx, const float* __restrict__ eww,
        const int* __restrict__ eoff, const int* __restrict__ elist,
        float* __restrict__ eraw) {
    int h = blockIdx.x, t = threadIdx.x;
    int s = eoff[h], e = eoff[h + 1];
    __shared__ float sBinv;
    if (t == 0) {
        float B = 0.f;
        for (int i = s; i < e; ++i) B += eww[hidx[elist[i]]];  // norm[node_idx]
        sBinv = (B == 0.f) ? 0.f : 1.f / B;
    }
    __syncthreads();
    float binv = sBinv;
    float4 a0 = make_float4(0, 0, 0, 0), a1 = a0, a2 = a0, a3 = a0;
    for (int i = s; i < e; ++i) {
        const float4* row = (const float4*)(feat + (size_t)hidx[elist[i]] * ND);
        float4 v0 = row[t], v1 = row[t + 256], v2 = row[t + 512], v3 = row[t + 768];
        a0.x += v0.x; a0.y += v0.y; a0.z += v0.z; a0.w += v0.w;
        a1.x += v1.x; a1.y += v1.y; a1.z += v1.z; a1.w += v1.w;
        a2.x += v2.x; a2.y += v2.y; a2.z += v2.z; a2.w += v2.w;
        a3.x += v3.x; a3.y += v3.y; a3.z += v3.z; a3.w += v3.w;
    }
    a0.x *= binv; a0.y *= binv; a0.z *= binv; a0.w *= binv;
    a1.x *= binv; a1.y *= binv; a1.z *= binv; a1.w *= binv;
    a2.x *= binv; a2.y *= binv; a2.z *= binv; a2.w *= binv;
    a3.x *= binv; a3.y *= binv; a3.z *= binv; a3.w *= binv;
    float4* out = (float4*)(eraw + (size_t)h * ND);
    out[t] = a0; out[t + 256] = a1; out[t + 512] = a2; out[t + 768] = a3;
}

// One block per node: node_out[n] = leaky(Dinv * sum_{incid} edge_raw[h] + bias)
__global__ void __launch_bounds__(256) node_k(const float* __restrict__ eraw,
        const int* __restrict__ hidx, const float* __restrict__ hw,
        const float* __restrict__ bias, const int* __restrict__ noff,
        const int* __restrict__ nlist, float* __restrict__ nout) {
    int n = blockIdx.x, t = threadIdx.x;
    int s = noff[n], e = noff[n + 1];
    __shared__ float sDinv;
    if (t == 0) {
        float D = 0.f;
        for (int i = s; i < e; ++i) D += hw[hidx[NI + nlist[i]]];  // hw[edge_idx]
        sDinv = (D == 0.f) ? 0.f : 1.f / D;
    }
    __syncthreads();
    float dinv = sDinv;
    float4 a0 = make_float4(0, 0, 0, 0), a1 = a0, a2 = a0, a3 = a0;
    for (int i = s; i < e; ++i) {
        const float4* row = (const float4*)(eraw + (size_t)hidx[NI + nlist[i]] * ND);
        float4 v0 = row[t], v1 = row[t + 256], v2 = row[t + 512], v3 = row[t + 768];
        a0.x += v0.x; a0.y += v0.y; a0.z += v0.z; a0.w += v0.w;
        a1.x += v1.x; a1.y += v1.y; a1.z += v1.z; a1.w += v1.w;
        a2.x += v2.x; a2.y += v2.y; a2.z += v2.z; a2.w += v2.w;
        a3.x += v3.x; a3.y += v3.y; a3.z += v3.z; a3.w += v3.w;
    }
    const float4* b4 = (const float4*)bias;
    float4* out = (float4*)(nout + (size_t)n * ND);
#define FIN(ak, idx)                                                     \
    {                                                                    \
        float4 b = b4[idx];                                              \
        float4 v;                                                        \
        v.x = dinv * ak.x + b.x; v.y = dinv * ak.y + b.y;                \
        v.z = dinv * ak.z + b.z; v.w = dinv * ak.w + b.w;                \
        v.x = v.x >= 0.f ? v.x : SLOPE * v.x;                            \
        v.y = v.y >= 0.f ? v.y : SLOPE * v.y;                            \
        v.z = v.z >= 0.f ? v.z : SLOPE * v.z;                            \
        v.w = v.w >= 0.f ? v.w : SLOPE * v.w;                            \
        out[idx] = v;                                                    \
    }
    FIN(a0, t);
    FIN(a1, t + 256);
    FIN(a2, t + 512);
    FIN(a3, t + 768);
#undef FIN
}

// In-place leaky relu on the edge section of d_out
__global__ void relu_k(float4* __restrict__ p, int n4) {
    int i = blockIdx.x * blockDim.x + threadIdx.x;
    if (i < n4) {
        float4 v = p[i];
        v.x = v.x >= 0.f ? v.x : SLOPE * v.x;
        v.y = v.y >= 0.f ? v.y : SLOPE * v.y;
        v.z = v.z >= 0.f ? v.z : SLOPE * v.z;
        v.w = v.w >= 0.f ? v.w : SLOPE * v.w;
        p[i] = v;
    }
}

extern "C" void kernel_launch(void* const* d_in, const int* in_sizes, int n_in,
                              void* d_out, int out_size, void* d_ws, size_t ws_size,
                              hipStream_t stream) {
    const float* feat = (const float*)d_in[0];   // (5200, 4096)
    const int* hidx   = (const int*)d_in[1];     // (2, 5200): [0..NI)=node, [NI..2NI)=edge
    const float* hw   = (const float*)d_in[3];   // hyperedge_weight (1000,)
    const float* eww  = (const float*)d_in[6];   // EW_weight (5200,)
    const float* bias = (const float*)d_in[7];   // (4096,)

    float* nout = (float*)d_out;                 // node output: NN*ND
    float* eraw = nout + (size_t)NN * ND;        // edge output (raw, then relu'd): NH*ND

    int* ws    = (int*)d_ws;
    int* ecnt  = ws;                 // NH
    int* ncnt  = ecnt + NH;          // NN
    int* eoff  = ncnt + NN;          // NH+1
    int* noff  = eoff + NH + 1;      // NN+1
    int* efill = noff + NN + 1;      // NH
    int* nfill = efill + NH;         // NN
    int* elist = nfill + NN;         // NI
    int* nlist = elist + NI;         // NI

    hipMemsetAsync(ecnt, 0, (size_t)(NH + NN) * sizeof(int), stream);
    count_k<<<(NI + 255) / 256, 256, 0, stream>>>(hidx, ecnt, ncnt);
    scan_k<<<1, 1024, 0, stream>>>(ecnt, ncnt, eoff, noff, efill, nfill);
    scatter_k<<<(NI + 255) / 256, 256, 0, stream>>>(hidx, efill, nfill, elist, nlist);
    edge_k<<<NH, 256, 0, stream>>>(feat, hidx, eww, eoff, elist, eraw);
    node_k<<<NN, 256, 0, stream>>>(eraw, hidx, hw, bias, noff, nlist, nout);
    relu_k<<<(NH * ND / 4 + 255) / 256, 256, 0, stream>>>((float4*)eraw, NH * ND / 4);
}

// Round 2
// 199.622 us; speedup vs baseline: 1.0699x; 1.0699x over previous
//
#include <hip/hip_runtime.h>

#define NN 5200   // nodes
#define NI 5200   // incidences
#define NH 1000   // hyperedges
#define ND 4096   // feature dim
#define SLOPE 0.01f
#define INV_SLOPE 100.0f

// ---------------- CSR build + degree sums ----------------

__global__ void count_k(const int* __restrict__ hidx, const float* __restrict__ hw,
                        const float* __restrict__ eww,
                        int* __restrict__ ecnt, int* __restrict__ ncnt,
                        float* __restrict__ Bsum, float* __restrict__ Dsum) {
    int i = blockIdx.x * blockDim.x + threadIdx.x;
    if (i < NI) {
        int n = hidx[i];        // node_idx
        int h = hidx[NI + i];   // edge_idx
        atomicAdd(&ncnt[n], 1);
        atomicAdd(&ecnt[h], 1);
        atomicAdd(&Dsum[n], hw[h]);    // D[n]  = sum hw[edge_idx]
        atomicAdd(&Bsum[h], eww[n]);   // B[h]  = sum EW_weight[node_idx]
    }
}

__device__ void scan_one(const int* __restrict__ cnt, int* __restrict__ off,
                         int* __restrict__ fill, int n, int* lds) {
    int t = threadIdx.x;
    int per = (n + 1023) >> 10;
    int base = t * per;
    int s = 0;
    for (int i = 0; i < per; ++i) {
        int id = base + i;
        if (id < n) s += cnt[id];
    }
    lds[t] = s;
    __syncthreads();
    for (int d = 1; d < 1024; d <<= 1) {
        int v = (t >= d) ? lds[t - d] : 0;
        __syncthreads();
        lds[t] += v;
        __syncthreads();
    }
    int total = lds[1023];
    int run = (t == 0) ? 0 : lds[t - 1];
    for (int i = 0; i < per; ++i) {
        int id = base + i;
        if (id < n) { off[id] = run; fill[id] = run; run += cnt[id]; }
    }
    if (t == 0) off[n] = total;
}

__global__ void __launch_bounds__(1024) scan_k(const int* ecnt, const int* ncnt,
                                               int* eoff, int* noff,
                                               int* efill, int* nfill) {
    __shared__ int lds[1024];
    scan_one(ecnt, eoff, efill, NH, lds);
    __syncthreads();
    scan_one(ncnt, noff, nfill, NN, lds);
}

// store TARGET ids directly: elist = node ids per edge, nlist = edge ids per node
__global__ void scatter_k(const int* __restrict__ hidx, int* __restrict__ efill,
                          int* __restrict__ nfill, int* __restrict__ elist,
                          int* __restrict__ nlist) {
    int i = blockIdx.x * blockDim.x + threadIdx.x;
    if (i < NI) {
        int n = hidx[i];
        int h = hidx[NI + i];
        int p = atomicAdd(&nfill[n], 1);
        nlist[p] = h;
        int q = atomicAdd(&efill[h], 1);
        elist[q] = n;
    }
}

// ---------------- heavy phases ----------------
// grid = NH*4; block bid handles edge h=bid>>2, float4 column range [part*256, part*256+256)
__global__ void __launch_bounds__(256) edge_k(const float* __restrict__ feat,
        const int* __restrict__ eoff, const int* __restrict__ elist,
        const float* __restrict__ Bsum, float* __restrict__ eout) {
    int bid = blockIdx.x;
    int h = bid >> 2;
    int col = ((bid & 3) << 8) + threadIdx.x;   // float4 index in row (0..1023)
    int s = eoff[h], e = eoff[h + 1];
    float B = Bsum[h];
    float binv = (B == 0.f) ? 0.f : 1.f / B;

    float4 acc = make_float4(0.f, 0.f, 0.f, 0.f);
    int i = s;
    int nid = (i < e) ? elist[i] : 0;
    for (; i < e; ++i) {
        int nid_next = (i + 1 < e) ? elist[i + 1] : 0;
        float4 v = ((const float4*)(feat + (size_t)nid * ND))[col];
        acc.x += v.x; acc.y += v.y; acc.z += v.z; acc.w += v.w;
        nid = nid_next;
    }
    // scale by Binv, apply leaky-relu, write final edge output
    float4 r;
    r.x = binv * acc.x; r.y = binv * acc.y; r.z = binv * acc.z; r.w = binv * acc.w;
    r.x = r.x >= 0.f ? r.x : SLOPE * r.x;
    r.y = r.y >= 0.f ? r.y : SLOPE * r.y;
    r.z = r.z >= 0.f ? r.z : SLOPE * r.z;
    r.w = r.w >= 0.f ? r.w : SLOPE * r.w;
    ((float4*)(eout + (size_t)h * ND))[col] = r;
}

// grid = NN*4; reads relu'd edge rows and inverts the activation on the fly
__global__ void __launch_bounds__(256) node_k(const float* __restrict__ eout,
        const int* __restrict__ noff, const int* __restrict__ nlist,
        const float* __restrict__ Dsum, const float* __restrict__ bias,
        float* __restrict__ nout) {
    int bid = blockIdx.x;
    int n = bid >> 2;
    int col = ((bid & 3) << 8) + threadIdx.x;
    int s = noff[n], e = noff[n + 1];
    float D = Dsum[n];
    float dinv = (D == 0.f) ? 0.f : 1.f / D;

    float4 acc = make_float4(0.f, 0.f, 0.f, 0.f);
    int i = s;
    int hid = (i < e) ? nlist[i] : 0;
    for (; i < e; ++i) {
        int hid_next = (i + 1 < e) ? nlist[i + 1] : 0;
        float4 v = ((const float4*)(eout + (size_t)hid * ND))[col];
        // invert leaky-relu to recover raw edge_out
        v.x = v.x >= 0.f ? v.x : INV_SLOPE * v.x;
        v.y = v.y >= 0.f ? v.y : INV_SLOPE * v.y;
        v.z = v.z >= 0.f ? v.z : INV_SLOPE * v.z;
        v.w = v.w >= 0.f ? v.w : INV_SLOPE * v.w;
        acc.x += v.x; acc.y += v.y; acc.z += v.z; acc.w += v.w;
        hid = hid_next;
    }
    float4 b = ((const float4*)bias)[col];
    float4 v;
    v.x = dinv * acc.x + b.x; v.y = dinv * acc.y + b.y;
    v.z = dinv * acc.z + b.z; v.w = dinv * acc.w + b.w;
    v.x = v.x >= 0.f ? v.x : SLOPE * v.x;
    v.y = v.y >= 0.f ? v.y : SLOPE * v.y;
    v.z = v.z >= 0.f ? v.z : SLOPE * v.z;
    v.w = v.w >= 0.f ? v.w : SLOPE * v.w;
    ((float4*)(nout + (size_t)n * ND))[col] = v;
}

extern "C" void kernel_launch(void* const* d_in, const int* in_sizes, int n_in,
                              void* d_out, int out_size, void* d_ws, size_t ws_size,
                              hipStream_t stream) {
    const float* feat = (const float*)d_in[0];   // (5200, 4096)
    const int* hidx   = (const int*)d_in[1];     // (2, 5200)
    const float* hw   = (const float*)d_in[3];   // hyperedge_weight (1000,)
    const float* eww  = (const float*)d_in[6];   // EW_weight (5200,)
    const float* bias = (const float*)d_in[7];   // (4096,)

    float* nout = (float*)d_out;                 // node output: NN*ND
    float* eout = nout + (size_t)NN * ND;        // edge output (relu'd): NH*ND

    int* ws      = (int*)d_ws;
    int* ecnt    = ws;                       // NH
    int* ncnt    = ecnt + NH;                // NN
    float* Bsum  = (float*)(ncnt + NN);      // NH
    float* Dsum  = Bsum + NH;                // NN
    int* eoff    = (int*)(Dsum + NN);        // NH+1
    int* noff    = eoff + NH + 1;            // NN+1
    int* efill   = noff + NN + 1;            // NH
    int* nfill   = efill + NH;               // NN
    int* elist   = nfill + NN;               // NI (node ids grouped by edge)
    int* nlist   = elist + NI;               // NI (edge ids grouped by node)

    // zero counts + float sums in one memset: 2*(NH+NN) words
    hipMemsetAsync(ecnt, 0, (size_t)2 * (NH + NN) * sizeof(int), stream);
    count_k<<<(NI + 255) / 256, 256, 0, stream>>>(hidx, hw, eww, ecnt, ncnt, Bsum, Dsum);
    scan_k<<<1, 1024, 0, stream>>>(ecnt, ncnt, eoff, noff, efill, nfill);
    scatter_k<<<(NI + 255) / 256, 256, 0, stream>>>(hidx, efill, nfill, elist, nlist);
    edge_k<<<NH * 4, 256, 0, stream>>>(feat, eoff, elist, Bsum, eout);
    node_k<<<NN * 4, 256, 0, stream>>>(eout, noff, nlist, Dsum, bias, nout);
}